// Round 1
// baseline (3710.329 us; speedup 1.0000x reference)
//
#include <hip/hip_runtime.h>

static constexpr int Dd = 128;   // feature dim
static constexpr int Hh = 64;    // MLP hidden
static constexpr int OC = 10;    // output classes
#define CDIV(a,b) (((a)+(b)-1)/(b))

__device__ __forceinline__ unsigned f2u(float f){ unsigned u=__float_as_uint(f); return (u&0x80000000u)? ~u : (u|0x80000000u); }
__device__ __forceinline__ float u2f(unsigned u){ return (u&0x80000000u)? __uint_as_float(u&0x7fffffffu) : __uint_as_float(~u); }
__device__ __forceinline__ float lrelu(float x){ return x>0.f? x : 0.2f*x; }

// ======================= edge kernels =======================
// 32 lanes per edge, float4 per lane (128 floats)
__global__ __launch_bounds__(256) void k_sage_scatter(const float* __restrict__ x,
    const int* __restrict__ src, const int* __restrict__ dst, int E,
    float* __restrict__ agg, float* __restrict__ cnt) {
  int gid = blockIdx.x*256 + threadIdx.x;
  int e = gid >> 5, lane = gid & 31;
  if (e >= E) return;
  int s = src[e], d = dst[e];
  float4 v = *reinterpret_cast<const float4*>(x + (size_t)s*Dd + lane*4);
  float* p = agg + (size_t)d*Dd + lane*4;
  atomicAdd(p+0, v.x); atomicAdd(p+1, v.y); atomicAdd(p+2, v.z); atomicAdd(p+3, v.w);
  if (lane == 0) atomicAdd(cnt + d, 1.0f);
}

__global__ __launch_bounds__(256) void k_gcn_scatter(const float* __restrict__ xw,
    const int* __restrict__ src, const int* __restrict__ dst, int E,
    const float* __restrict__ dinv, float* __restrict__ out) {
  int gid = blockIdx.x*256 + threadIdx.x;
  int e = gid >> 5, lane = gid & 31;
  if (e >= E) return;
  int s = src[e], d = dst[e];
  float w = dinv[s]*dinv[d];
  float4 v = *reinterpret_cast<const float4*>(xw + (size_t)s*Dd + lane*4);
  float* p = out + (size_t)d*Dd + lane*4;
  atomicAdd(p+0, v.x*w); atomicAdd(p+1, v.y*w); atomicAdd(p+2, v.z*w); atomicAdd(p+3, v.w*w);
}

__global__ __launch_bounds__(256) void k_gat_max(const int* __restrict__ src,
    const int* __restrict__ dst, int E,
    const float* __restrict__ a_s, const float* __restrict__ a_d,
    unsigned* __restrict__ m_u) {
  int e = blockIdx.x*256 + threadIdx.x;
  if (e >= E) return;
  int s = src[e], d = dst[e];
  float ev = lrelu(a_s[s] + a_d[d]);
  atomicMax(m_u + d, f2u(ev));
}

__global__ __launch_bounds__(256) void k_gat_scatter(const float* __restrict__ xw,
    const int* __restrict__ src, const int* __restrict__ dst, int E,
    const float* __restrict__ a_s, const float* __restrict__ a_d,
    const float* __restrict__ m, float* __restrict__ z, float* __restrict__ out) {
  int gid = blockIdx.x*256 + threadIdx.x;
  int e = gid >> 5, lane = gid & 31;
  if (e >= E) return;
  int s = src[e], d = dst[e];
  float w = expf(lrelu(a_s[s] + a_d[d]) - m[d]);
  if (lane == 0) atomicAdd(z + d, w);
  float4 v = *reinterpret_cast<const float4*>(xw + (size_t)s*Dd + lane*4);
  float* p = out + (size_t)d*Dd + lane*4;
  atomicAdd(p+0, v.x*w); atomicAdd(p+1, v.y*w); atomicAdd(p+2, v.z*w); atomicAdd(p+3, v.w*w);
}

// ======================= node elementwise =======================
__global__ __launch_bounds__(256) void k_mean(float* __restrict__ agg,
    const float* __restrict__ cnt, int nf4) {
  int idx = blockIdx.x*256 + threadIdx.x;
  if (idx >= nf4) return;
  int row = idx >> 5;
  float inv = 1.0f / fmaxf(cnt[row], 1.0f);
  float4* p = reinterpret_cast<float4*>(agg) + idx;
  float4 v = *p; v.x*=inv; v.y*=inv; v.z*=inv; v.w*=inv; *p = v;
}

__global__ __launch_bounds__(256) void k_dinv(const float* __restrict__ cnt,
    float* __restrict__ dinv, int n) {
  int i = blockIdx.x*256 + threadIdx.x;
  if (i < n) dinv[i] = rsqrtf(cnt[i] + 1.0f);   // deg = in-degree + self loop >= 1
}

// out[i,:] = xw[i,:] * dinv[i]^2   (GCN self-loop term, also zero-inits out)
__global__ __launch_bounds__(256) void k_gcn_init(const float* __restrict__ xw,
    const float* __restrict__ dinv, float* __restrict__ out, int nf4) {
  int idx = blockIdx.x*256 + threadIdx.x;
  if (idx >= nf4) return;
  int row = idx >> 5;
  float w = dinv[row]*dinv[row];
  float4 v = reinterpret_cast<const float4*>(xw)[idx];
  v.x*=w; v.y*=w; v.z*=w; v.w*=w;
  reinterpret_cast<float4*>(out)[idx] = v;
}

// m_u[i] = key(self-loop score)
__global__ __launch_bounds__(256) void k_gat_init_m(const float* __restrict__ a_s,
    const float* __restrict__ a_d, unsigned* __restrict__ m_u, int n) {
  int i = blockIdx.x*256 + threadIdx.x;
  if (i < n) m_u[i] = f2u(lrelu(a_s[i] + a_d[i]));
}

// decode max to float (in place), z[i] = exp(e_self - m)
__global__ __launch_bounds__(256) void k_gat_prep(const float* __restrict__ a_s,
    const float* __restrict__ a_d, unsigned* __restrict__ m_u,
    float* __restrict__ z, int n) {
  int i = blockIdx.x*256 + threadIdx.x;
  if (i >= n) return;
  float mf = u2f(m_u[i]);
  reinterpret_cast<float*>(m_u)[i] = mf;
  float e0 = lrelu(a_s[i] + a_d[i]);
  z[i] = expf(e0 - mf);
}

// out[i,:] = z0[i] * xw[i,:]  (self-loop numerator term; zero-inits out)
__global__ __launch_bounds__(256) void k_gat_init_feat(const float* __restrict__ xw,
    const float* __restrict__ z, float* __restrict__ out, int nf4) {
  int idx = blockIdx.x*256 + threadIdx.x;
  if (idx >= nf4) return;
  int row = idx >> 5;
  float w = z[row];
  float4 v = reinterpret_cast<const float4*>(xw)[idx];
  v.x*=w; v.y*=w; v.z*=w; v.w*=w;
  reinterpret_cast<float4*>(out)[idx] = v;
}

__global__ __launch_bounds__(256) void k_gat_fin(float* __restrict__ out,
    const float* __restrict__ z, int nf4) {
  int idx = blockIdx.x*256 + threadIdx.x;
  if (idx >= nf4) return;
  int row = idx >> 5;
  float inv = 1.0f / z[row];
  float4* p = reinterpret_cast<float4*>(out) + idx;
  float4 v = *p; v.x*=inv; v.y*=inv; v.z*=inv; v.w*=inv; *p = v;
}

// ======================= batch norm =======================
__global__ __launch_bounds__(256) void k_bn_stats(const float* __restrict__ X, int M,
    float* __restrict__ gsum, float* __restrict__ gsq) {
  __shared__ float ssum[256], ssq[256];
  int col = threadIdx.x & 127, half = threadIdx.x >> 7;
  float s = 0.f, q = 0.f;
  for (int r = blockIdx.x*2 + half; r < M; r += gridDim.x*2) {
    float v = X[(size_t)r*Dd + col];
    s += v; q += v*v;
  }
  ssum[threadIdx.x] = s; ssq[threadIdx.x] = q;
  __syncthreads();
  if (threadIdx.x < 128) {
    atomicAdd(gsum + col, ssum[threadIdx.x] + ssum[threadIdx.x+128]);
    atomicAdd(gsq  + col, ssq[threadIdx.x]  + ssq[threadIdx.x+128]);
  }
}

__global__ __launch_bounds__(128) void k_bn_final(const float* __restrict__ gsum,
    const float* __restrict__ gsq, int M, const float* __restrict__ g,
    const float* __restrict__ b, float* __restrict__ scale, float* __restrict__ shift) {
  int c = threadIdx.x;
  float mu = gsum[c] / (float)M;
  float var = fmaxf(gsq[c] / (float)M - mu*mu, 0.f);
  float sc = g[c] * rsqrtf(var + 1e-5f);
  scale[c] = sc;
  shift[c] = b[c] - mu*sc;
}

__global__ __launch_bounds__(256) void k_bn_apply_relu(float* __restrict__ X,
    const float* __restrict__ scale, const float* __restrict__ shift, int nf4) {
  int idx = blockIdx.x*256 + threadIdx.x;
  if (idx >= nf4) return;
  int c4 = idx & 31;
  float4 sc = reinterpret_cast<const float4*>(scale)[c4];
  float4 sh = reinterpret_cast<const float4*>(shift)[c4];
  float4* p = reinterpret_cast<float4*>(X) + idx;
  float4 v = *p;
  v.x = fmaxf(v.x*sc.x + sh.x, 0.f);
  v.y = fmaxf(v.y*sc.y + sh.y, 0.f);
  v.z = fmaxf(v.z*sc.z + sh.z, 0.f);
  v.w = fmaxf(v.w*sc.w + sh.w, 0.f);
  *p = v;
}

// ======================= GEMM: C[M][NCOLS] (+)= A[M][128] @ W[128][NCOLS] =======================
template<int NCOLS, bool ACCUM, bool RELU_BIAS>
__global__ __launch_bounds__(256) void k_gemm128(const float* __restrict__ A,
    const float* __restrict__ W, const float* __restrict__ bias,
    float* __restrict__ C, int M) {
  constexpr int BK = 32, BM = 64;
  constexpr int TX = NCOLS/4;        // col groups of 4
  constexpr int ROWG = 256/TX;
  constexpr int TM = BM/ROWG;        // rows per thread
  __shared__ float As[BM][BK+1];
  __shared__ float Ws[BK][NCOLS];
  int t = threadIdx.x;
  int tx = t % TX, ty = t / TX;
  int row0 = blockIdx.x * BM;
  float acc[TM][4];
  #pragma unroll
  for (int i=0;i<TM;i++){acc[i][0]=0;acc[i][1]=0;acc[i][2]=0;acc[i][3]=0;}

  for (int k0 = 0; k0 < 128; k0 += BK) {
    // load A tile: BM x BK
    #pragma unroll
    for (int i = 0; i < (BM*BK)/(4*256); i++) {
      int q = t + i*256;
      int row = q >> 3, kc = q & 7;          // 8 float4 per row
      float4 v = {0,0,0,0};
      if (row0 + row < M)
        v = *reinterpret_cast<const float4*>(A + (size_t)(row0+row)*128 + k0 + kc*4);
      As[row][kc*4+0]=v.x; As[row][kc*4+1]=v.y; As[row][kc*4+2]=v.z; As[row][kc*4+3]=v.w;
    }
    // load W tile: BK x NCOLS (always in range)
    #pragma unroll
    for (int i = 0; i < (BK*NCOLS)/(4*256); i++) {
      int q = t + i*256;
      int row = q / TX, c4 = q % TX;
      *reinterpret_cast<float4*>(&Ws[row][c4*4]) =
        *reinterpret_cast<const float4*>(W + (size_t)(k0+row)*NCOLS + c4*4);
    }
    __syncthreads();
    #pragma unroll
    for (int kk = 0; kk < BK; kk++) {
      float4 wv = *reinterpret_cast<const float4*>(&Ws[kk][tx*4]);
      #pragma unroll
      for (int i = 0; i < TM; i++) {
        float a = As[ty*TM+i][kk];
        acc[i][0] += a*wv.x; acc[i][1] += a*wv.y; acc[i][2] += a*wv.z; acc[i][3] += a*wv.w;
      }
    }
    __syncthreads();
  }
  // epilogue
  float4 bv = {0,0,0,0};
  if (RELU_BIAS) bv = *reinterpret_cast<const float4*>(bias + tx*4);
  #pragma unroll
  for (int i = 0; i < TM; i++) {
    int row = row0 + ty*TM + i;
    if (row >= M) continue;
    float4 r; r.x=acc[i][0]; r.y=acc[i][1]; r.z=acc[i][2]; r.w=acc[i][3];
    float4* cp = reinterpret_cast<float4*>(C + (size_t)row*NCOLS + tx*4);
    if (ACCUM) { float4 c0 = *cp; r.x+=c0.x; r.y+=c0.y; r.z+=c0.z; r.w+=c0.w; }
    if (RELU_BIAS) {
      r.x = fmaxf(r.x+bv.x, 0.f); r.y = fmaxf(r.y+bv.y, 0.f);
      r.z = fmaxf(r.z+bv.z, 0.f); r.w = fmaxf(r.w+bv.w, 0.f);
    }
    *cp = r;
  }
}

// ======================= GAT attention dots =======================
// a_s[i] = dot(xw[i,:], att_s), a_d[i] = dot(xw[i,:], att_d); one wave per row
__global__ __launch_bounds__(256) void k_att(const float* __restrict__ xw,
    const float* __restrict__ att_s, const float* __restrict__ att_d,
    float* __restrict__ a_s, float* __restrict__ a_d, int n) {
  int row = blockIdx.x*4 + (threadIdx.x >> 6);
  int lane = threadIdx.x & 63;
  if (row >= n) return;
  float v0 = xw[(size_t)row*Dd + lane];
  float v1 = xw[(size_t)row*Dd + 64 + lane];
  float ps = v0*att_s[lane] + v1*att_s[64+lane];
  float pd = v0*att_d[lane] + v1*att_d[64+lane];
  #pragma unroll
  for (int m = 32; m >= 1; m >>= 1) {
    ps += __shfl_xor(ps, m);
    pd += __shfl_xor(pd, m);
  }
  if (lane == 0) { a_s[row] = ps; a_d[row] = pd; }
}

// ======================= MLP head: logits + log_softmax =======================
// one wave per row: m1[row,0:64] -> 10 logits -> log_softmax -> out
__global__ __launch_bounds__(256) void k_head(const float* __restrict__ M1,
    const float* __restrict__ W2, const float* __restrict__ b2,
    float* __restrict__ out, int n) {
  __shared__ float w2s[Hh*OC];
  __shared__ float b2s[OC];
  for (int i = threadIdx.x; i < Hh*OC; i += 256) w2s[i] = W2[i];
  if (threadIdx.x < OC) b2s[threadIdx.x] = b2[threadIdx.x];
  __syncthreads();
  int row = blockIdx.x*4 + (threadIdx.x >> 6);
  int lane = threadIdx.x & 63;
  if (row >= n) return;
  float v = M1[(size_t)row*Hh + lane];
  float p[OC];
  #pragma unroll
  for (int c = 0; c < OC; c++) p[c] = v * w2s[lane*OC + c];
  #pragma unroll
  for (int c = 0; c < OC; c++) {
    p[c] += __shfl_down(p[c], 32);
    p[c] += __shfl_down(p[c], 16);
    p[c] += __shfl_down(p[c], 8);
    p[c] += __shfl_down(p[c], 4);
    p[c] += __shfl_down(p[c], 2);
    p[c] += __shfl_down(p[c], 1);
  }
  if (lane == 0) {
    float mx = -1e30f;
    #pragma unroll
    for (int c = 0; c < OC; c++) { p[c] += b2s[c]; mx = fmaxf(mx, p[c]); }
    float s = 0.f;
    #pragma unroll
    for (int c = 0; c < OC; c++) s += expf(p[c] - mx);
    float lse = mx + logf(s);
    #pragma unroll
    for (int c = 0; c < OC; c++) out[(size_t)row*OC + c] = p[c] - lse;
  }
}

// ======================= launch =======================
extern "C" void kernel_launch(void* const* d_in, const int* in_sizes, int n_in,
                              void* d_out, int out_size, void* d_ws, size_t ws_size,
                              hipStream_t stream) {
  const float* x       = (const float*)d_in[0];
  const int*   ei      = (const int*)d_in[1];
  const float* sage_Wl = (const float*)d_in[2];
  const float* sage_Wr = (const float*)d_in[3];
  // d_in[4] = sage_b: zero AND absorbed by BN -> skipped
  const float* gcn_W   = (const float*)d_in[5];
  // d_in[6] = gcn_b: absorbed by BN
  const float* gat_W   = (const float*)d_in[7];
  const float* att_s   = (const float*)d_in[8];
  const float* att_d   = (const float*)d_in[9];
  // d_in[10] = gat_b: absorbed by BN
  const float* bn1_g = (const float*)d_in[11], *bn1_b = (const float*)d_in[12];
  const float* bn2_g = (const float*)d_in[13], *bn2_b = (const float*)d_in[14];
  const float* bn3_g = (const float*)d_in[15], *bn3_b = (const float*)d_in[16];
  const float* lin1_W = (const float*)d_in[17], *lin1_b = (const float*)d_in[18];
  const float* lin2_W = (const float*)d_in[19], *lin2_b = (const float*)d_in[20];

  const int Nn = in_sizes[0] / Dd;     // 100000
  const int Ee = in_sizes[1] / 2;      // 600000
  const int* srcv = ei;
  const int* dstv = ei + Ee;

  float* wsf   = (float*)d_ws;
  float* buf0  = wsf;                          // N*D
  float* buf1  = buf0 + (size_t)Nn*Dd;         // N*D
  float* cnt   = buf1 + (size_t)Nn*Dd;         // N
  float* dinv  = cnt + Nn;                     // N
  float* a_s   = dinv + Nn;                    // N
  float* a_d   = a_s + Nn;                     // N
  float* zbuf  = a_d + Nn;                     // N
  float* mbuf  = zbuf + Nn;                    // N (uint keys, then float max)
  float* bn_sum   = mbuf + Nn;                 // 128
  float* bn_sq    = bn_sum + Dd;               // 128
  float* bn_scale = bn_sq + Dd;                // 128
  float* bn_shift = bn_scale + Dd;             // 128

  const int nf4 = Nn * (Dd/4);                 // N*32 float4 elements
  const dim3 B(256);
  const dim3 Gnf4(CDIV(nf4, 256));
  const dim3 Gn(CDIV(Nn, 256));
  const dim3 Ge32(CDIV(Ee*32, 256));
  const dim3 Ge(CDIV(Ee, 256));
  const dim3 Ggemm(CDIV(Nn, 64));
  const dim3 Grow4(CDIV(Nn, 4));

  auto bn = [&](float* buf, const float* g, const float* b) {
    hipMemsetAsync(bn_sum, 0, 2*Dd*sizeof(float), stream);
    k_bn_stats<<<dim3(1024), B, 0, stream>>>(buf, Nn, bn_sum, bn_sq);
    k_bn_final<<<dim3(1), dim3(128), 0, stream>>>(bn_sum, bn_sq, Nn, g, b, bn_scale, bn_shift);
    k_bn_apply_relu<<<Gnf4, B, 0, stream>>>(buf, bn_scale, bn_shift, nf4);
  };

  // ---------- Layer 1: SAGE ----------
  hipMemsetAsync(buf0, 0, (size_t)Nn*Dd*sizeof(float), stream);   // agg
  hipMemsetAsync(cnt, 0, (size_t)Nn*sizeof(float), stream);
  k_sage_scatter<<<Ge32, B, 0, stream>>>(x, srcv, dstv, Ee, buf0, cnt);
  k_mean<<<Gnf4, B, 0, stream>>>(buf0, cnt, nf4);
  k_gemm128<Dd, false, false><<<Ggemm, B, 0, stream>>>(buf0, sage_Wl, nullptr, buf1, Nn);
  k_gemm128<Dd, true,  false><<<Ggemm, B, 0, stream>>>(x,    sage_Wr, nullptr, buf1, Nn);
  bn(buf1, bn1_g, bn1_b);                                          // h1 in buf1

  // ---------- Layer 2: GCN ----------
  k_dinv<<<Gn, B, 0, stream>>>(cnt, dinv, Nn);
  k_gemm128<Dd, false, false><<<Ggemm, B, 0, stream>>>(buf1, gcn_W, nullptr, buf0, Nn); // xw
  k_gcn_init<<<Gnf4, B, 0, stream>>>(buf0, dinv, buf1, nf4);       // overwrite h1
  k_gcn_scatter<<<Ge32, B, 0, stream>>>(buf0, srcv, dstv, Ee, dinv, buf1);
  bn(buf1, bn2_g, bn2_b);                                          // h2 in buf1

  // ---------- Layer 3: GAT ----------
  k_gemm128<Dd, false, false><<<Ggemm, B, 0, stream>>>(buf1, gat_W, nullptr, buf0, Nn); // xw
  k_att<<<Grow4, B, 0, stream>>>(buf0, att_s, att_d, a_s, a_d, Nn);
  k_gat_init_m<<<Gn, B, 0, stream>>>(a_s, a_d, (unsigned*)mbuf, Nn);
  k_gat_max<<<Ge, B, 0, stream>>>(srcv, dstv, Ee, a_s, a_d, (unsigned*)mbuf);
  k_gat_prep<<<Gn, B, 0, stream>>>(a_s, a_d, (unsigned*)mbuf, zbuf, Nn);
  k_gat_init_feat<<<Gnf4, B, 0, stream>>>(buf0, zbuf, buf1, nf4);  // overwrite h2
  k_gat_scatter<<<Ge32, B, 0, stream>>>(buf0, srcv, dstv, Ee, a_s, a_d, mbuf, zbuf, buf1);
  k_gat_fin<<<Gnf4, B, 0, stream>>>(buf1, zbuf, nf4);
  bn(buf1, bn3_g, bn3_b);                                          // h3 in buf1

  // ---------- MLP head ----------
  k_gemm128<Hh, false, true><<<Ggemm, B, 0, stream>>>(buf1, lin1_W, lin1_b, buf0, Nn); // m1 (N x 64)
  k_head<<<Grow4, B, 0, stream>>>(buf0, lin2_W, lin2_b, (float*)d_out, Nn);
}

// Round 2
// 767.603 us; speedup vs baseline: 4.8337x; 4.8337x over previous
//
#include <hip/hip_runtime.h>

static constexpr int Dd = 128;   // feature dim
static constexpr int Hh = 64;    // MLP hidden
static constexpr int OC = 10;    // output classes
#define CDIV(a,b) (((a)+(b)-1)/(b))

__device__ __forceinline__ float lrelu(float x){ return x>0.f? x : 0.2f*x; }

// ======================= CSR build =======================
__global__ __launch_bounds__(256) void k_hist(const int* __restrict__ dst, int E,
    int* __restrict__ cnt) {
  int e = blockIdx.x*256 + threadIdx.x;
  if (e < E) atomicAdd(cnt + dst[e], 1);
}

// level-1 scan: each block scans 2048 ints (256 thr x 8), local exclusive into rp,
// block total into bsum
__global__ __launch_bounds__(256) void k_scan_l1(const int* __restrict__ cnt,
    int* __restrict__ rp, int n, int* __restrict__ bsum) {
  __shared__ int sdata[256];
  int t = threadIdx.x;
  int base = blockIdx.x*2048 + t*8;
  int v[8]; int s = 0;
  #pragma unroll
  for (int k = 0; k < 8; k++) { v[k] = (base+k < n) ? cnt[base+k] : 0; s += v[k]; }
  sdata[t] = s; __syncthreads();
  for (int off = 1; off < 256; off <<= 1) {
    int a = sdata[t];
    int b = (t >= off) ? sdata[t-off] : 0;
    __syncthreads();
    sdata[t] = a + b;
    __syncthreads();
  }
  int ex = sdata[t] - s;              // exclusive prefix of this thread
  if (t == 255) bsum[blockIdx.x] = sdata[255];
  int run = ex;
  #pragma unroll
  for (int k = 0; k < 8; k++) { if (base+k < n) rp[base+k] = run; run += v[k]; }
}

__global__ void k_scan_l2(int* __restrict__ bsum, int nb) {
  if (threadIdx.x == 0 && blockIdx.x == 0) {
    int run = 0;
    for (int i = 0; i < nb; i++) { int v = bsum[i]; bsum[i] = run; run += v; }
  }
}

__global__ __launch_bounds__(256) void k_scan_l3(int* __restrict__ rp, int n,
    const int* __restrict__ bsum, int E) {
  int off = bsum[blockIdx.x];
  int base = blockIdx.x*2048 + threadIdx.x*8;
  #pragma unroll
  for (int k = 0; k < 8; k++) if (base+k < n) rp[base+k] += off;
  if (blockIdx.x == 0 && threadIdx.x == 0) rp[n] = E;
}

// scatter edges into CSR slots; cnt (counts) consumed down to zero
__global__ __launch_bounds__(256) void k_fill(const int* __restrict__ src,
    const int* __restrict__ dst, int E, const int* __restrict__ rp,
    int* __restrict__ cnt, int* __restrict__ col) {
  int e = blockIdx.x*256 + threadIdx.x;
  if (e >= E) return;
  int d = dst[e];
  int pos = rp[d] + atomicSub(cnt + d, 1) - 1;
  col[pos] = src[e];
}

// ======================= per-node gather aggregations =======================
// 32 lanes per node, float4 per lane
__global__ __launch_bounds__(256) void k_sage_gather(const float* __restrict__ x,
    const int* __restrict__ rp, const int* __restrict__ col,
    float* __restrict__ out, int n) {
  int gid = blockIdx.x*256 + threadIdx.x;
  int i = gid >> 5, l = gid & 31;
  if (i >= n) return;
  int beg = rp[i], end = rp[i+1];
  float4 acc = {0,0,0,0};
  for (int j = beg; j < end; j++) {
    int s = col[j];
    float4 v = *reinterpret_cast<const float4*>(x + (size_t)s*Dd + l*4);
    acc.x += v.x; acc.y += v.y; acc.z += v.z; acc.w += v.w;
  }
  float inv = 1.0f / fmaxf((float)(end - beg), 1.0f);
  acc.x *= inv; acc.y *= inv; acc.z *= inv; acc.w *= inv;
  *reinterpret_cast<float4*>(out + (size_t)i*Dd + l*4) = acc;
}

__global__ __launch_bounds__(256) void k_dinv(const int* __restrict__ rp,
    float* __restrict__ dinv, int n) {
  int i = blockIdx.x*256 + threadIdx.x;
  if (i < n) dinv[i] = rsqrtf((float)(rp[i+1] - rp[i]) + 1.0f);  // deg + self loop
}

__global__ __launch_bounds__(256) void k_gcn_gather(const float* __restrict__ xw,
    const int* __restrict__ rp, const int* __restrict__ col,
    const float* __restrict__ dinv, float* __restrict__ out, int n) {
  int gid = blockIdx.x*256 + threadIdx.x;
  int i = gid >> 5, l = gid & 31;
  if (i >= n) return;
  int beg = rp[i], end = rp[i+1];
  float4 acc = {0,0,0,0};
  for (int j = beg; j < end; j++) {
    int s = col[j];
    float w = dinv[s];
    float4 v = *reinterpret_cast<const float4*>(xw + (size_t)s*Dd + l*4);
    acc.x += w*v.x; acc.y += w*v.y; acc.z += w*v.z; acc.w += w*v.w;
  }
  float di = dinv[i];
  float ws = di*di;
  float4 sv = *reinterpret_cast<const float4*>(xw + (size_t)i*Dd + l*4);
  acc.x = di*acc.x + ws*sv.x; acc.y = di*acc.y + ws*sv.y;
  acc.z = di*acc.z + ws*sv.z; acc.w = di*acc.w + ws*sv.w;
  *reinterpret_cast<float4*>(out + (size_t)i*Dd + l*4) = acc;
}

__global__ __launch_bounds__(256) void k_gat_gather(const float* __restrict__ xw,
    const int* __restrict__ rp, const int* __restrict__ col,
    const float* __restrict__ a_s, const float* __restrict__ a_d,
    float* __restrict__ out, int n) {
  int gid = blockIdx.x*256 + threadIdx.x;
  int i = gid >> 5, l = gid & 31;
  if (i >= n) return;
  int beg = rp[i], end = rp[i+1];
  float ad = a_d[i];
  float es = lrelu(a_s[i] + ad);         // self-loop score
  float m = es;
  for (int j = beg; j < end; j++)
    m = fmaxf(m, lrelu(a_s[col[j]] + ad));
  float z = expf(es - m);
  float4 sv = *reinterpret_cast<const float4*>(xw + (size_t)i*Dd + l*4);
  float4 acc; acc.x = z*sv.x; acc.y = z*sv.y; acc.z = z*sv.z; acc.w = z*sv.w;
  for (int j = beg; j < end; j++) {
    int s = col[j];
    float w = expf(lrelu(a_s[s] + ad) - m);
    z += w;
    float4 v = *reinterpret_cast<const float4*>(xw + (size_t)s*Dd + l*4);
    acc.x += w*v.x; acc.y += w*v.y; acc.z += w*v.z; acc.w += w*v.w;
  }
  float inv = 1.0f / z;
  acc.x *= inv; acc.y *= inv; acc.z *= inv; acc.w *= inv;
  *reinterpret_cast<float4*>(out + (size_t)i*Dd + l*4) = acc;
}

// ======================= batch norm =======================
__global__ __launch_bounds__(256) void k_bn_stats(const float* __restrict__ X, int M,
    float* __restrict__ gsum, float* __restrict__ gsq) {
  __shared__ float ssum[256], ssq[256];
  int col = threadIdx.x & 127, half = threadIdx.x >> 7;
  float s = 0.f, q = 0.f;
  for (int r = blockIdx.x*2 + half; r < M; r += gridDim.x*2) {
    float v = X[(size_t)r*Dd + col];
    s += v; q += v*v;
  }
  ssum[threadIdx.x] = s; ssq[threadIdx.x] = q;
  __syncthreads();
  if (threadIdx.x < 128) {
    atomicAdd(gsum + col, ssum[threadIdx.x] + ssum[threadIdx.x+128]);
    atomicAdd(gsq  + col, ssq[threadIdx.x]  + ssq[threadIdx.x+128]);
  }
}

__global__ __launch_bounds__(128) void k_bn_final(const float* __restrict__ gsum,
    const float* __restrict__ gsq, int M, const float* __restrict__ g,
    const float* __restrict__ b, float* __restrict__ scale, float* __restrict__ shift) {
  int c = threadIdx.x;
  float mu = gsum[c] / (float)M;
  float var = fmaxf(gsq[c] / (float)M - mu*mu, 0.f);
  float sc = g[c] * rsqrtf(var + 1e-5f);
  scale[c] = sc;
  shift[c] = b[c] - mu*sc;
}

__global__ __launch_bounds__(256) void k_bn_apply_relu(float* __restrict__ X,
    const float* __restrict__ scale, const float* __restrict__ shift, int nf4) {
  int idx = blockIdx.x*256 + threadIdx.x;
  if (idx >= nf4) return;
  int c4 = idx & 31;
  float4 sc = reinterpret_cast<const float4*>(scale)[c4];
  float4 sh = reinterpret_cast<const float4*>(shift)[c4];
  float4* p = reinterpret_cast<float4*>(X) + idx;
  float4 v = *p;
  v.x = fmaxf(v.x*sc.x + sh.x, 0.f);
  v.y = fmaxf(v.y*sc.y + sh.y, 0.f);
  v.z = fmaxf(v.z*sc.z + sh.z, 0.f);
  v.w = fmaxf(v.w*sc.w + sh.w, 0.f);
  *p = v;
}

// ======================= GEMM: C[M][NCOLS] (+)= A[M][128] @ W[128][NCOLS] =======================
template<int NCOLS, bool ACCUM, bool RELU_BIAS>
__global__ __launch_bounds__(256) void k_gemm128(const float* __restrict__ A,
    const float* __restrict__ W, const float* __restrict__ bias,
    float* __restrict__ C, int M) {
  constexpr int BK = 32, BM = 64;
  constexpr int TX = NCOLS/4;        // col groups of 4
  constexpr int ROWG = 256/TX;
  constexpr int TM = BM/ROWG;        // rows per thread
  __shared__ float As[BM][BK+1];
  __shared__ float Ws[BK][NCOLS];
  int t = threadIdx.x;
  int tx = t % TX, ty = t / TX;
  int row0 = blockIdx.x * BM;
  float acc[TM][4];
  #pragma unroll
  for (int i=0;i<TM;i++){acc[i][0]=0;acc[i][1]=0;acc[i][2]=0;acc[i][3]=0;}

  for (int k0 = 0; k0 < 128; k0 += BK) {
    #pragma unroll
    for (int i = 0; i < (BM*BK)/(4*256); i++) {
      int q = t + i*256;
      int row = q >> 3, kc = q & 7;
      float4 v = {0,0,0,0};
      if (row0 + row < M)
        v = *reinterpret_cast<const float4*>(A + (size_t)(row0+row)*128 + k0 + kc*4);
      As[row][kc*4+0]=v.x; As[row][kc*4+1]=v.y; As[row][kc*4+2]=v.z; As[row][kc*4+3]=v.w;
    }
    #pragma unroll
    for (int i = 0; i < (BK*NCOLS)/(4*256); i++) {
      int q = t + i*256;
      int row = q / TX, c4 = q % TX;
      *reinterpret_cast<float4*>(&Ws[row][c4*4]) =
        *reinterpret_cast<const float4*>(W + (size_t)(k0+row)*NCOLS + c4*4);
    }
    __syncthreads();
    #pragma unroll
    for (int kk = 0; kk < BK; kk++) {
      float4 wv = *reinterpret_cast<const float4*>(&Ws[kk][tx*4]);
      #pragma unroll
      for (int i = 0; i < TM; i++) {
        float a = As[ty*TM+i][kk];
        acc[i][0] += a*wv.x; acc[i][1] += a*wv.y; acc[i][2] += a*wv.z; acc[i][3] += a*wv.w;
      }
    }
    __syncthreads();
  }
  float4 bv = {0,0,0,0};
  if (RELU_BIAS) bv = *reinterpret_cast<const float4*>(bias + tx*4);
  #pragma unroll
  for (int i = 0; i < TM; i++) {
    int row = row0 + ty*TM + i;
    if (row >= M) continue;
    float4 r; r.x=acc[i][0]; r.y=acc[i][1]; r.z=acc[i][2]; r.w=acc[i][3];
    float4* cp = reinterpret_cast<float4*>(C + (size_t)row*NCOLS + tx*4);
    if (ACCUM) { float4 c0 = *cp; r.x+=c0.x; r.y+=c0.y; r.z+=c0.z; r.w+=c0.w; }
    if (RELU_BIAS) {
      r.x = fmaxf(r.x+bv.x, 0.f); r.y = fmaxf(r.y+bv.y, 0.f);
      r.z = fmaxf(r.z+bv.z, 0.f); r.w = fmaxf(r.w+bv.w, 0.f);
    }
    *cp = r;
  }
}

// ======================= GAT attention dots =======================
__global__ __launch_bounds__(256) void k_att(const float* __restrict__ xw,
    const float* __restrict__ att_s, const float* __restrict__ att_d,
    float* __restrict__ a_s, float* __restrict__ a_d, int n) {
  int row = blockIdx.x*4 + (threadIdx.x >> 6);
  int lane = threadIdx.x & 63;
  if (row >= n) return;
  float v0 = xw[(size_t)row*Dd + lane];
  float v1 = xw[(size_t)row*Dd + 64 + lane];
  float ps = v0*att_s[lane] + v1*att_s[64+lane];
  float pd = v0*att_d[lane] + v1*att_d[64+lane];
  #pragma unroll
  for (int m = 32; m >= 1; m >>= 1) {
    ps += __shfl_xor(ps, m);
    pd += __shfl_xor(pd, m);
  }
  if (lane == 0) { a_s[row] = ps; a_d[row] = pd; }
}

// ======================= MLP head =======================
__global__ __launch_bounds__(256) void k_head(const float* __restrict__ M1,
    const float* __restrict__ W2, const float* __restrict__ b2,
    float* __restrict__ out, int n) {
  __shared__ float w2s[Hh*OC];
  __shared__ float b2s[OC];
  for (int i = threadIdx.x; i < Hh*OC; i += 256) w2s[i] = W2[i];
  if (threadIdx.x < OC) b2s[threadIdx.x] = b2[threadIdx.x];
  __syncthreads();
  int row = blockIdx.x*4 + (threadIdx.x >> 6);
  int lane = threadIdx.x & 63;
  if (row >= n) return;
  float v = M1[(size_t)row*Hh + lane];
  float p[OC];
  #pragma unroll
  for (int c = 0; c < OC; c++) p[c] = v * w2s[lane*OC + c];
  #pragma unroll
  for (int c = 0; c < OC; c++) {
    p[c] += __shfl_down(p[c], 32);
    p[c] += __shfl_down(p[c], 16);
    p[c] += __shfl_down(p[c], 8);
    p[c] += __shfl_down(p[c], 4);
    p[c] += __shfl_down(p[c], 2);
    p[c] += __shfl_down(p[c], 1);
  }
  if (lane == 0) {
    float mx = -1e30f;
    #pragma unroll
    for (int c = 0; c < OC; c++) { p[c] += b2s[c]; mx = fmaxf(mx, p[c]); }
    float s = 0.f;
    #pragma unroll
    for (int c = 0; c < OC; c++) s += expf(p[c] - mx);
    float lse = mx + logf(s);
    #pragma unroll
    for (int c = 0; c < OC; c++) out[(size_t)row*OC + c] = p[c] - lse;
  }
}

// ======================= launch =======================
extern "C" void kernel_launch(void* const* d_in, const int* in_sizes, int n_in,
                              void* d_out, int out_size, void* d_ws, size_t ws_size,
                              hipStream_t stream) {
  const float* x       = (const float*)d_in[0];
  const int*   ei      = (const int*)d_in[1];
  const float* sage_Wl = (const float*)d_in[2];
  const float* sage_Wr = (const float*)d_in[3];
  const float* gcn_W   = (const float*)d_in[5];
  const float* gat_W   = (const float*)d_in[7];
  const float* att_s   = (const float*)d_in[8];
  const float* att_d   = (const float*)d_in[9];
  const float* bn1_g = (const float*)d_in[11], *bn1_b = (const float*)d_in[12];
  const float* bn2_g = (const float*)d_in[13], *bn2_b = (const float*)d_in[14];
  const float* bn3_g = (const float*)d_in[15], *bn3_b = (const float*)d_in[16];
  const float* lin1_W = (const float*)d_in[17], *lin1_b = (const float*)d_in[18];
  const float* lin2_W = (const float*)d_in[19], *lin2_b = (const float*)d_in[20];

  const int Nn = in_sizes[0] / Dd;     // 100000
  const int Ee = in_sizes[1] / 2;      // 600000
  const int* srcv = ei;
  const int* dstv = ei + Ee;

  float* wsf   = (float*)d_ws;
  float* buf0  = wsf;                          // N*D
  float* buf1  = buf0 + (size_t)Nn*Dd;         // N*D
  float* dinv  = buf1 + (size_t)Nn*Dd;         // N
  float* a_s   = dinv + Nn;                    // N
  float* a_d   = a_s + Nn;                     // N
  float* bn_sum   = a_d + Nn;                  // 128
  float* bn_sq    = bn_sum + Dd;               // 128
  float* bn_scale = bn_sq + Dd;                // 128
  float* bn_shift = bn_scale + Dd;             // 128
  int* rp    = (int*)(bn_shift + Dd);          // N+1
  int* cnt_i = rp + (Nn + 1);                  // N
  int* bsum  = cnt_i + Nn;                     // 64
  int* col   = bsum + 64;                      // E

  const int nf4 = Nn * (Dd/4);
  const dim3 B(256);
  const dim3 Gnf4(CDIV(nf4, 256));
  const dim3 Gn(CDIV(Nn, 256));
  const dim3 Gn32(CDIV(Nn*32, 256));
  const dim3 Ge(CDIV(Ee, 256));
  const dim3 Ggemm(CDIV(Nn, 64));
  const dim3 Grow4(CDIV(Nn, 4));
  const int nscan = CDIV(Nn, 2048);

  auto bn = [&](float* buf, const float* g, const float* b) {
    hipMemsetAsync(bn_sum, 0, 2*Dd*sizeof(float), stream);
    k_bn_stats<<<dim3(1024), B, 0, stream>>>(buf, Nn, bn_sum, bn_sq);
    k_bn_final<<<dim3(1), dim3(128), 0, stream>>>(bn_sum, bn_sq, Nn, g, b, bn_scale, bn_shift);
    k_bn_apply_relu<<<Gnf4, B, 0, stream>>>(buf, bn_scale, bn_shift, nf4);
  };

  // ---------- CSR build (dst-sorted, stores src) ----------
  hipMemsetAsync(cnt_i, 0, (size_t)Nn*sizeof(int), stream);
  k_hist<<<Ge, B, 0, stream>>>(dstv, Ee, cnt_i);
  k_scan_l1<<<dim3(nscan), B, 0, stream>>>(cnt_i, rp, Nn, bsum);
  k_scan_l2<<<dim3(1), dim3(64), 0, stream>>>(bsum, nscan);
  k_scan_l3<<<dim3(nscan), B, 0, stream>>>(rp, Nn, bsum, Ee);
  k_fill<<<Ge, B, 0, stream>>>(srcv, dstv, Ee, rp, cnt_i, col);

  // ---------- Layer 1: SAGE ----------
  k_sage_gather<<<Gn32, B, 0, stream>>>(x, rp, col, buf0, Nn);
  k_gemm128<Dd, false, false><<<Ggemm, B, 0, stream>>>(buf0, sage_Wl, nullptr, buf1, Nn);
  k_gemm128<Dd, true,  false><<<Ggemm, B, 0, stream>>>(x,    sage_Wr, nullptr, buf1, Nn);
  bn(buf1, bn1_g, bn1_b);                                          // h1 in buf1

  // ---------- Layer 2: GCN ----------
  k_dinv<<<Gn, B, 0, stream>>>(rp, dinv, Nn);
  k_gemm128<Dd, false, false><<<Ggemm, B, 0, stream>>>(buf1, gcn_W, nullptr, buf0, Nn); // xw
  k_gcn_gather<<<Gn32, B, 0, stream>>>(buf0, rp, col, dinv, buf1, Nn);
  bn(buf1, bn2_g, bn2_b);                                          // h2 in buf1

  // ---------- Layer 3: GAT ----------
  k_gemm128<Dd, false, false><<<Ggemm, B, 0, stream>>>(buf1, gat_W, nullptr, buf0, Nn); // xw
  k_att<<<Grow4, B, 0, stream>>>(buf0, att_s, att_d, a_s, a_d, Nn);
  k_gat_gather<<<Gn32, B, 0, stream>>>(buf0, rp, col, a_s, a_d, buf1, Nn);
  bn(buf1, bn3_g, bn3_b);                                          // h3 in buf1

  // ---------- MLP head ----------
  k_gemm128<Hh, false, true><<<Ggemm, B, 0, stream>>>(buf1, lin1_W, lin1_b, buf0, Nn); // m1
  k_head<<<Grow4, B, 0, stream>>>(buf0, lin2_W, lin2_b, (float*)d_out, Nn);
}

// Round 3
// 506.330 us; speedup vs baseline: 7.3279x; 1.5160x over previous
//
#include <hip/hip_runtime.h>

static constexpr int Dd = 128;   // feature dim
static constexpr int Hh = 64;    // MLP hidden
static constexpr int OC = 10;    // output classes
#define CDIV(a,b) (((a)+(b)-1)/(b))

typedef __attribute__((ext_vector_type(8))) short short8v;
typedef __attribute__((ext_vector_type(16))) float f32x16;

__device__ __forceinline__ float lrelu(float x){ return x>0.f? x : 0.2f*x; }
__device__ __forceinline__ unsigned short f2bf(float f){
  unsigned u = __float_as_uint(f);
  return (unsigned short)((u + 0x7FFFu + ((u>>16)&1u)) >> 16);
}
// XOR swizzle: spread row-major stride-256B column reads across 8 16B slots
__device__ __forceinline__ int swz(int byte, int row){ return byte ^ ((row&7)<<4); }

// ======================= CSR build =======================
__global__ __launch_bounds__(256) void k_hist(const int* __restrict__ dst, int E,
    int* __restrict__ cnt) {
  int e = blockIdx.x*256 + threadIdx.x;
  if (e < E) atomicAdd(cnt + dst[e], 1);
}

__global__ __launch_bounds__(256) void k_scan_l1(const int* __restrict__ cnt,
    int* __restrict__ rp, int n, int* __restrict__ bsum) {
  __shared__ int sdata[256];
  int t = threadIdx.x;
  int base = blockIdx.x*2048 + t*8;
  int v[8]; int s = 0;
  #pragma unroll
  for (int k = 0; k < 8; k++) { v[k] = (base+k < n) ? cnt[base+k] : 0; s += v[k]; }
  sdata[t] = s; __syncthreads();
  for (int off = 1; off < 256; off <<= 1) {
    int a = sdata[t];
    int b = (t >= off) ? sdata[t-off] : 0;
    __syncthreads();
    sdata[t] = a + b;
    __syncthreads();
  }
  int ex = sdata[t] - s;
  if (t == 255) bsum[blockIdx.x] = sdata[255];
  int run = ex;
  #pragma unroll
  for (int k = 0; k < 8; k++) { if (base+k < n) rp[base+k] = run; run += v[k]; }
}

__global__ void k_scan_l2(int* __restrict__ bsum, int nb) {
  if (threadIdx.x == 0 && blockIdx.x == 0) {
    int run = 0;
    for (int i = 0; i < nb; i++) { int v = bsum[i]; bsum[i] = run; run += v; }
  }
}

__global__ __launch_bounds__(256) void k_scan_l3(int* __restrict__ rp, int n,
    const int* __restrict__ bsum, int E) {
  int off = bsum[blockIdx.x];
  int base = blockIdx.x*2048 + threadIdx.x*8;
  #pragma unroll
  for (int k = 0; k < 8; k++) if (base+k < n) rp[base+k] += off;
  if (blockIdx.x == 0 && threadIdx.x == 0) rp[n] = E;
}

__global__ __launch_bounds__(256) void k_fill(const int* __restrict__ src,
    const int* __restrict__ dst, int E, const int* __restrict__ rp,
    int* __restrict__ cnt, int* __restrict__ col) {
  int e = blockIdx.x*256 + threadIdx.x;
  if (e >= E) return;
  int d = dst[e];
  int pos = rp[d] + atomicSub(cnt + d, 1) - 1;
  col[pos] = src[e];
}

// ======================= weight prep: WT[n][k] = bf16(W[k][n]) =======================
__global__ __launch_bounds__(256) void k_wt(const float* __restrict__ W,
    unsigned short* __restrict__ WT, int K, int N) {
  int idx = blockIdx.x*256 + threadIdx.x;
  if (idx >= K*N) return;
  int n = idx / K, k = idx % K;          // output-major
  WT[idx] = f2bf(W[k*N + n]);
}

// ======================= per-node gather aggregations =======================
__global__ __launch_bounds__(256) void k_sage_gather(const float* __restrict__ x,
    const int* __restrict__ rp, const int* __restrict__ col,
    float* __restrict__ out, int n) {
  int gid = blockIdx.x*256 + threadIdx.x;
  int i = gid >> 5, l = gid & 31;
  if (i >= n) return;
  int beg = rp[i], end = rp[i+1];
  float4 acc = {0,0,0,0};
  for (int j = beg; j < end; j++) {
    int s = col[j];
    float4 v = *reinterpret_cast<const float4*>(x + (size_t)s*Dd + l*4);
    acc.x += v.x; acc.y += v.y; acc.z += v.z; acc.w += v.w;
  }
  float inv = 1.0f / fmaxf((float)(end - beg), 1.0f);
  acc.x *= inv; acc.y *= inv; acc.z *= inv; acc.w *= inv;
  *reinterpret_cast<float4*>(out + (size_t)i*Dd + l*4) = acc;
}

__global__ __launch_bounds__(256) void k_dinv(const int* __restrict__ rp,
    float* __restrict__ dinv, int n) {
  int i = blockIdx.x*256 + threadIdx.x;
  if (i < n) dinv[i] = rsqrtf((float)(rp[i+1] - rp[i]) + 1.0f);
}

__global__ __launch_bounds__(256) void k_gcn_gather(const float* __restrict__ xw,
    const int* __restrict__ rp, const int* __restrict__ col,
    const float* __restrict__ dinv, float* __restrict__ out, int n) {
  int gid = blockIdx.x*256 + threadIdx.x;
  int i = gid >> 5, l = gid & 31;
  if (i >= n) return;
  int beg = rp[i], end = rp[i+1];
  float4 acc = {0,0,0,0};
  for (int j = beg; j < end; j++) {
    int s = col[j];
    float w = dinv[s];
    float4 v = *reinterpret_cast<const float4*>(xw + (size_t)s*Dd + l*4);
    acc.x += w*v.x; acc.y += w*v.y; acc.z += w*v.z; acc.w += w*v.w;
  }
  float di = dinv[i];
  float ws = di*di;
  float4 sv = *reinterpret_cast<const float4*>(xw + (size_t)i*Dd + l*4);
  acc.x = di*acc.x + ws*sv.x; acc.y = di*acc.y + ws*sv.y;
  acc.z = di*acc.z + ws*sv.z; acc.w = di*acc.w + ws*sv.w;
  *reinterpret_cast<float4*>(out + (size_t)i*Dd + l*4) = acc;
}

__global__ __launch_bounds__(256) void k_gat_gather(const float* __restrict__ xw,
    const int* __restrict__ rp, const int* __restrict__ col,
    const float* __restrict__ a_s, const float* __restrict__ a_d,
    float* __restrict__ out, int n) {
  int gid = blockIdx.x*256 + threadIdx.x;
  int i = gid >> 5, l = gid & 31;
  if (i >= n) return;
  int beg = rp[i], end = rp[i+1];
  float ad = a_d[i];
  float es = lrelu(a_s[i] + ad);
  float m = es;
  for (int j = beg; j < end; j++)
    m = fmaxf(m, lrelu(a_s[col[j]] + ad));
  float z = expf(es - m);
  float4 sv = *reinterpret_cast<const float4*>(xw + (size_t)i*Dd + l*4);
  float4 acc; acc.x = z*sv.x; acc.y = z*sv.y; acc.z = z*sv.z; acc.w = z*sv.w;
  for (int j = beg; j < end; j++) {
    int s = col[j];
    float w = expf(lrelu(a_s[s] + ad) - m);
    z += w;
    float4 v = *reinterpret_cast<const float4*>(xw + (size_t)s*Dd + l*4);
    acc.x += w*v.x; acc.y += w*v.y; acc.z += w*v.z; acc.w += w*v.w;
  }
  float inv = 1.0f / z;
  acc.x *= inv; acc.y *= inv; acc.z *= inv; acc.w *= inv;
  *reinterpret_cast<float4*>(out + (size_t)i*Dd + l*4) = acc;
}

// ======================= batch norm (stats + final) =======================
__global__ __launch_bounds__(256) void k_bn_stats(const float* __restrict__ X, int M,
    float* __restrict__ gsum, float* __restrict__ gsq) {
  __shared__ float ssum[256], ssq[256];
  int col = threadIdx.x & 127, half = threadIdx.x >> 7;
  float s = 0.f, q = 0.f;
  for (int r = blockIdx.x*2 + half; r < M; r += gridDim.x*2) {
    float v = X[(size_t)r*Dd + col];
    s += v; q += v*v;
  }
  ssum[threadIdx.x] = s; ssq[threadIdx.x] = q;
  __syncthreads();
  if (threadIdx.x < 128) {
    atomicAdd(gsum + col, ssum[threadIdx.x] + ssum[threadIdx.x+128]);
    atomicAdd(gsq  + col, ssq[threadIdx.x]  + ssq[threadIdx.x+128]);
  }
}

__global__ __launch_bounds__(128) void k_bn_final(const float* __restrict__ gsum,
    const float* __restrict__ gsq, int M, const float* __restrict__ g,
    const float* __restrict__ b, float* __restrict__ scale, float* __restrict__ shift) {
  int c = threadIdx.x;
  float mu = gsum[c] / (float)M;
  float var = fmaxf(gsq[c] / (float)M - mu*mu, 0.f);
  float sc = g[c] * rsqrtf(var + 1e-5f);
  scale[c] = sc;
  shift[c] = b[c] - mu*sc;
}

// ======================= MFMA GEMM =======================
// C[M][NCOLS] = A1'[M][128] @ W1[128][NCOLS]  (+ A2'@W2 if DUAL)
// A' = BNA ? relu(A*scale+shift) : A   (converted to bf16 on the fly)
// WT layout: [NCOLS][128] bf16 (pre-transposed). STATS: atomic col sums of C.
template<int NCOLS, bool DUAL, bool BNA, bool STATS, bool BIASRELU>
__global__ __launch_bounds__(256) void k_mm(
    const float* __restrict__ A1, const float* __restrict__ A2,
    const unsigned short* __restrict__ WT1, const unsigned short* __restrict__ WT2,
    const float* __restrict__ bnsc, const float* __restrict__ bnsh,
    const float* __restrict__ bias,
    float* __restrict__ C, int M,
    float* __restrict__ gsum, float* __restrict__ gsq) {
  constexpr int NF = NCOLS/32;
  __shared__ char ldsA[128*128*2];
  __shared__ char ldsW[NCOLS*128*2];
  int t = threadIdx.x;
  int wave = t >> 6, l = t & 63;
  int lm = l & 31, h = l >> 5;
  int row0 = blockIdx.x*128;

  f32x16 acc[NF];
  #pragma unroll
  for (int nf = 0; nf < NF; nf++)
    #pragma unroll
    for (int i = 0; i < 16; i++) acc[nf][i] = 0.f;

  const int nph = DUAL ? 2 : 1;
  for (int ph = 0; ph < nph; ph++) {
    const float* A = (DUAL && ph) ? A2 : A1;
    const unsigned short* WT = (DUAL && ph) ? WT2 : WT1;
    // ---- stage W tile: NCOLS x 128 bf16, swizzled ----
    #pragma unroll
    for (int i = 0; i < NCOLS*16/256; i++) {
      int c = i*256 + t; int nrow = c >> 4; int k0 = (c & 15) << 3;
      uint4 w = *reinterpret_cast<const uint4*>(WT + nrow*128 + k0);
      *reinterpret_cast<uint4*>(ldsW + swz(nrow*256 + k0*2, nrow)) = w;
    }
    // ---- stage A tile: 128 x 128, fp32 -> (BN+relu) -> bf16, swizzled ----
    #pragma unroll
    for (int i = 0; i < 8; i++) {
      int c = i*256 + t; int row = c >> 4; int k0 = (c & 15) << 3;
      float4 v0 = {0,0,0,0}, v1 = {0,0,0,0};
      if (row0 + row < M) {
        const float* p = A + (size_t)(row0+row)*128 + k0;
        v0 = *reinterpret_cast<const float4*>(p);
        v1 = *reinterpret_cast<const float4*>(p+4);
      }
      if constexpr (BNA) {
        float4 sc0 = *reinterpret_cast<const float4*>(bnsc + k0);
        float4 sc1 = *reinterpret_cast<const float4*>(bnsc + k0 + 4);
        float4 sh0 = *reinterpret_cast<const float4*>(bnsh + k0);
        float4 sh1 = *reinterpret_cast<const float4*>(bnsh + k0 + 4);
        v0.x = fmaxf(v0.x*sc0.x+sh0.x, 0.f); v0.y = fmaxf(v0.y*sc0.y+sh0.y, 0.f);
        v0.z = fmaxf(v0.z*sc0.z+sh0.z, 0.f); v0.w = fmaxf(v0.w*sc0.w+sh0.w, 0.f);
        v1.x = fmaxf(v1.x*sc1.x+sh1.x, 0.f); v1.y = fmaxf(v1.y*sc1.y+sh1.y, 0.f);
        v1.z = fmaxf(v1.z*sc1.z+sh1.z, 0.f); v1.w = fmaxf(v1.w*sc1.w+sh1.w, 0.f);
      }
      uint4 w;
      w.x = (unsigned)f2bf(v0.x) | ((unsigned)f2bf(v0.y) << 16);
      w.y = (unsigned)f2bf(v0.z) | ((unsigned)f2bf(v0.w) << 16);
      w.z = (unsigned)f2bf(v1.x) | ((unsigned)f2bf(v1.y) << 16);
      w.w = (unsigned)f2bf(v1.z) | ((unsigned)f2bf(v1.w) << 16);
      *reinterpret_cast<uint4*>(ldsA + swz(row*256 + k0*2, row)) = w;
    }
    __syncthreads();
    // ---- compute: 8 k-steps of K=16 ----
    #pragma unroll
    for (int ks = 0; ks < 8; ks++) {
      int kb = (ks*16 + h*8) * 2;      // byte offset of k-chunk
      int arow = wave*32 + lm;
      short8v af = *reinterpret_cast<short8v*>(ldsA + swz(arow*256 + kb, arow));
      #pragma unroll
      for (int nf = 0; nf < NF; nf++) {
        int brow = nf*32 + lm;
        short8v bf = *reinterpret_cast<short8v*>(ldsW + swz(brow*256 + kb, brow));
        acc[nf] = __builtin_amdgcn_mfma_f32_32x32x16_bf16(af, bf, acc[nf], 0, 0, 0);
      }
    }
    __syncthreads();
  }
  // ---- epilogue ----
  float* s_sum = reinterpret_cast<float*>(ldsW);
  float* s_sq  = s_sum + 128;
  if constexpr (STATS) {
    if (t < 128) { s_sum[t] = 0.f; s_sq[t] = 0.f; }
    __syncthreads();
  }
  #pragma unroll
  for (int nf = 0; nf < NF; nf++) {
    int colg = nf*32 + lm;
    float bv = 0.f;
    if constexpr (BIASRELU) bv = bias[colg];
    float ps = 0.f, pq = 0.f;
    #pragma unroll
    for (int reg = 0; reg < 16; reg++) {
      int row = row0 + wave*32 + (reg&3) + 8*(reg>>2) + 4*h;
      float v = acc[nf][reg];
      if constexpr (BIASRELU) v = fmaxf(v + bv, 0.f);
      if (row < M) C[(size_t)row*NCOLS + colg] = v;
      ps += v; pq += v*v;                 // padded rows are exact zeros
    }
    if constexpr (STATS) {
      atomicAdd(&s_sum[colg], ps);
      atomicAdd(&s_sq[colg], pq);
    }
  }
  if constexpr (STATS) {
    __syncthreads();
    if (t < 128) { atomicAdd(gsum + t, s_sum[t]); atomicAdd(gsq + t, s_sq[t]); }
  }
}

// ======================= GAT attention dots =======================
__global__ __launch_bounds__(256) void k_att(const float* __restrict__ xw,
    const float* __restrict__ att_s, const float* __restrict__ att_d,
    float* __restrict__ a_s, float* __restrict__ a_d, int n) {
  int row = blockIdx.x*4 + (threadIdx.x >> 6);
  int lane = threadIdx.x & 63;
  if (row >= n) return;
  float v0 = xw[(size_t)row*Dd + lane];
  float v1 = xw[(size_t)row*Dd + 64 + lane];
  float ps = v0*att_s[lane] + v1*att_s[64+lane];
  float pd = v0*att_d[lane] + v1*att_d[64+lane];
  #pragma unroll
  for (int m = 32; m >= 1; m >>= 1) {
    ps += __shfl_xor(ps, m);
    pd += __shfl_xor(pd, m);
  }
  if (lane == 0) { a_s[row] = ps; a_d[row] = pd; }
}

// ======================= head: lin2 + log_softmax, one thread per row =======================
__global__ __launch_bounds__(256) void k_head2(const float* __restrict__ M1,
    const float* __restrict__ W2, const float* __restrict__ b2,
    float* __restrict__ out, int n) {
  __shared__ float rows[256][65];
  __shared__ float w2s[Hh][OC];
  __shared__ float b2s[OC];
  int t = threadIdx.x;
  for (int i = t; i < Hh*OC; i += 256) w2s[i/OC][i%OC] = W2[i];
  if (t < OC) b2s[t] = b2[t];
  int r0 = blockIdx.x*256;
  #pragma unroll
  for (int i = 0; i < 16; i++) {
    int f = i*256 + t; int row = f >> 4; int c0 = (f & 15) << 2;
    float4 v = {0,0,0,0};
    if (r0 + row < n) v = *reinterpret_cast<const float4*>(M1 + (size_t)(r0+row)*Hh + c0);
    rows[row][c0+0] = v.x; rows[row][c0+1] = v.y;
    rows[row][c0+2] = v.z; rows[row][c0+3] = v.w;
  }
  __syncthreads();
  int row = r0 + t;
  if (row >= n) return;
  float p[OC];
  #pragma unroll
  for (int c = 0; c < OC; c++) p[c] = b2s[c];
  for (int k = 0; k < Hh; k++) {
    float a = rows[t][k];
    #pragma unroll
    for (int c = 0; c < OC; c++) p[c] += a * w2s[k][c];
  }
  float mx = p[0];
  #pragma unroll
  for (int c = 1; c < OC; c++) mx = fmaxf(mx, p[c]);
  float s = 0.f;
  #pragma unroll
  for (int c = 0; c < OC; c++) s += expf(p[c] - mx);
  float lse = mx + logf(s);
  #pragma unroll
  for (int c = 0; c < OC; c++) out[(size_t)row*OC + c] = p[c] - lse;
}

// ======================= launch =======================
extern "C" void kernel_launch(void* const* d_in, const int* in_sizes, int n_in,
                              void* d_out, int out_size, void* d_ws, size_t ws_size,
                              hipStream_t stream) {
  const float* x       = (const float*)d_in[0];
  const int*   ei      = (const int*)d_in[1];
  const float* sage_Wl = (const float*)d_in[2];
  const float* sage_Wr = (const float*)d_in[3];
  const float* gcn_W   = (const float*)d_in[5];
  const float* gat_W   = (const float*)d_in[7];
  const float* att_s   = (const float*)d_in[8];
  const float* att_d   = (const float*)d_in[9];
  const float* bn1_g = (const float*)d_in[11], *bn1_b = (const float*)d_in[12];
  const float* bn2_g = (const float*)d_in[13], *bn2_b = (const float*)d_in[14];
  const float* bn3_g = (const float*)d_in[15], *bn3_b = (const float*)d_in[16];
  const float* lin1_W = (const float*)d_in[17], *lin1_b = (const float*)d_in[18];
  const float* lin2_W = (const float*)d_in[19], *lin2_b = (const float*)d_in[20];

  const int Nn = in_sizes[0] / Dd;     // 100000
  const int Ee = in_sizes[1] / 2;      // 600000
  const int* srcv = ei;
  const int* dstv = ei + Ee;

  float* wsf   = (float*)d_ws;
  float* buf0  = wsf;                          // N*D
  float* buf1  = buf0 + (size_t)Nn*Dd;         // N*D
  float* dinv  = buf1 + (size_t)Nn*Dd;         // N
  float* a_s   = dinv + Nn;                    // N
  float* a_d   = a_s + Nn;                     // N
  float* bn_sum   = a_d + Nn;                  // 128
  float* bn_sq    = bn_sum + Dd;               // 128
  float* bn_scale = bn_sq + Dd;                // 128
  float* bn_shift = bn_scale + Dd;             // 128
  int* rp    = (int*)(bn_shift + Dd);          // N+1
  int* cnt_i = rp + (Nn + 1);                  // N
  int* bsum  = cnt_i + Nn;                     // 64
  int* col   = bsum + 64;                      // E
  unsigned short* wt_sWl = (unsigned short*)(col + Ee);   // 128*128 each
  unsigned short* wt_sWr = wt_sWl + 128*128;
  unsigned short* wt_gcn = wt_sWr + 128*128;
  unsigned short* wt_gat = wt_gcn + 128*128;
  unsigned short* wt_l1  = wt_gat + 128*128;              // 64*128

  const dim3 B(256);
  const dim3 Gn(CDIV(Nn, 256));
  const dim3 Gn32(CDIV(Nn*32, 256));
  const dim3 Ge(CDIV(Ee, 256));
  const dim3 Gmm(CDIV(Nn, 128));
  const dim3 Grow4(CDIV(Nn, 4));
  const dim3 Ghead(CDIV(Nn, 256));
  const int nscan = CDIV(Nn, 2048);

  // ---------- CSR build + weight prep ----------
  hipMemsetAsync(cnt_i, 0, (size_t)Nn*sizeof(int), stream);
  k_hist<<<Ge, B, 0, stream>>>(dstv, Ee, cnt_i);
  k_scan_l1<<<dim3(nscan), B, 0, stream>>>(cnt_i, rp, Nn, bsum);
  k_scan_l2<<<dim3(1), dim3(64), 0, stream>>>(bsum, nscan);
  k_scan_l3<<<dim3(nscan), B, 0, stream>>>(rp, Nn, bsum, Ee);
  k_fill<<<Ge, B, 0, stream>>>(srcv, dstv, Ee, rp, cnt_i, col);
  k_wt<<<dim3(64), B, 0, stream>>>(sage_Wl, wt_sWl, 128, 128);
  k_wt<<<dim3(64), B, 0, stream>>>(sage_Wr, wt_sWr, 128, 128);
  k_wt<<<dim3(64), B, 0, stream>>>(gcn_W,   wt_gcn, 128, 128);
  k_wt<<<dim3(64), B, 0, stream>>>(gat_W,   wt_gat, 128, 128);
  k_wt<<<dim3(32), B, 0, stream>>>(lin1_W,  wt_l1,  128, 64);

  // ---------- Layer 1: SAGE ----------
  k_sage_gather<<<Gn32, B, 0, stream>>>(x, rp, col, buf0, Nn);
  hipMemsetAsync(bn_sum, 0, 2*Dd*sizeof(float), stream);
  // pre1 = mean@Wl + x@Wr, col-stats fused
  k_mm<128, true, false, true, false><<<Gmm, B, 0, stream>>>(
      buf0, x, wt_sWl, wt_sWr, nullptr, nullptr, nullptr, buf1, Nn, bn_sum, bn_sq);
  k_bn_final<<<dim3(1), dim3(128), 0, stream>>>(bn_sum, bn_sq, Nn, bn1_g, bn1_b, bn_scale, bn_shift);

  // ---------- Layer 2: GCN ----------
  k_dinv<<<Gn, B, 0, stream>>>(rp, dinv, Nn);
  // xw2 = BNReLU(pre1)@gcn_W
  k_mm<128, false, true, false, false><<<Gmm, B, 0, stream>>>(
      buf1, nullptr, wt_gcn, nullptr, bn_scale, bn_shift, nullptr, buf0, Nn, nullptr, nullptr);
  k_gcn_gather<<<Gn32, B, 0, stream>>>(buf0, rp, col, dinv, buf1, Nn);   // pre2
  hipMemsetAsync(bn_sum, 0, 2*Dd*sizeof(float), stream);
  k_bn_stats<<<dim3(1024), B, 0, stream>>>(buf1, Nn, bn_sum, bn_sq);
  k_bn_final<<<dim3(1), dim3(128), 0, stream>>>(bn_sum, bn_sq, Nn, bn2_g, bn2_b, bn_scale, bn_shift);

  // ---------- Layer 3: GAT ----------
  // xw3 = BNReLU(pre2)@gat_W
  k_mm<128, false, true, false, false><<<Gmm, B, 0, stream>>>(
      buf1, nullptr, wt_gat, nullptr, bn_scale, bn_shift, nullptr, buf0, Nn, nullptr, nullptr);
  k_att<<<Grow4, B, 0, stream>>>(buf0, att_s, att_d, a_s, a_d, Nn);
  k_gat_gather<<<Gn32, B, 0, stream>>>(buf0, rp, col, a_s, a_d, buf1, Nn);  // pre3
  hipMemsetAsync(bn_sum, 0, 2*Dd*sizeof(float), stream);
  k_bn_stats<<<dim3(1024), B, 0, stream>>>(buf1, Nn, bn_sum, bn_sq);
  k_bn_final<<<dim3(1), dim3(128), 0, stream>>>(bn_sum, bn_sq, Nn, bn3_g, bn3_b, bn_scale, bn_shift);

  // ---------- MLP head ----------
  // m1 = relu(BNReLU(pre3)@lin1_W + b1)
  k_mm<64, false, true, false, true><<<Gmm, B, 0, stream>>>(
      buf1, nullptr, wt_l1, nullptr, bn_scale, bn_shift, lin1_b, buf0, Nn, nullptr, nullptr);
  k_head2<<<Ghead, B, 0, stream>>>(buf0, lin2_W, lin2_b, (float*)d_out, Nn);
}